// Round 1
// baseline (283.676 us; speedup 1.0000x reference)
//
#include <hip/hip_runtime.h>

// Problem constants (from reference setup_inputs):
// inputs  [N=64, C=3, H=128, W=128] fp32
// samples [N=64, S=16, C=3, H=128, W=128] fp32
// out: scalar fp32 = sum_n min_s sum_chw (samples[n,s]-inputs[n])^2
constexpr int N_BATCH = 64;
constexpr int S_SAMP  = 16;
constexpr int CHW     = 3 * 128 * 128;   // 49152 floats per (n,s) pair
constexpr int CHW4    = CHW / 4;         // 12288 float4

// Kernel 1: one block per (n,s) pair. 1024 blocks x 256 threads.
// Each thread: 48 float4 loads of samples + matching inputs, fp32 accumulate,
// wave-64 shuffle reduce, 4 wave partials via LDS, write ws[b].
__global__ __launch_bounds__(256) void pair_sqdist_kernel(
    const float* __restrict__ inputs,
    const float* __restrict__ samples,
    float* __restrict__ ws)
{
    const int b = blockIdx.x;            // b = n*16 + s
    const int n = b >> 4;
    const float4* __restrict__ inp = reinterpret_cast<const float4*>(inputs + (size_t)n * CHW);
    const float4* __restrict__ smp = reinterpret_cast<const float4*>(samples + (size_t)b * CHW);

    const int t = threadIdx.x;
    float acc = 0.0f;
    #pragma unroll 4
    for (int i = t; i < CHW4; i += 256) {
        float4 a = inp[i];
        float4 c = smp[i];
        float dx = c.x - a.x;
        float dy = c.y - a.y;
        float dz = c.z - a.z;
        float dw = c.w - a.w;
        acc += dx * dx + dy * dy + dz * dz + dw * dw;
    }

    // wave-64 butterfly reduce
    #pragma unroll
    for (int off = 32; off > 0; off >>= 1)
        acc += __shfl_down(acc, off, 64);

    __shared__ float wave_part[4];
    const int wave = t >> 6;
    if ((t & 63) == 0) wave_part[wave] = acc;
    __syncthreads();
    if (t == 0) {
        ws[b] = wave_part[0] + wave_part[1] + wave_part[2] + wave_part[3];
    }
}

// Kernel 2: one block of 64 threads. Thread n: min over its 16 sample losses,
// then wave-64 sum reduce, lane 0 writes the scalar.
__global__ __launch_bounds__(64) void min_sum_kernel(
    const float* __restrict__ ws,
    float* __restrict__ out)
{
    const int n = threadIdx.x;           // 0..63
    const float* p = ws + n * S_SAMP;
    float m = p[0];
    #pragma unroll
    for (int s = 1; s < S_SAMP; ++s)
        m = fminf(m, p[s]);
    #pragma unroll
    for (int off = 32; off > 0; off >>= 1)
        m += __shfl_down(m, off, 64);
    if (n == 0) out[0] = m;
}

extern "C" void kernel_launch(void* const* d_in, const int* in_sizes, int n_in,
                              void* d_out, int out_size, void* d_ws, size_t ws_size,
                              hipStream_t stream) {
    const float* inputs  = (const float*)d_in[0];  // [64,3,128,128]
    const float* samples = (const float*)d_in[1];  // [64,16,3,128,128]
    float* out = (float*)d_out;                    // [1]
    float* ws  = (float*)d_ws;                     // need 1024 floats = 4 KB

    pair_sqdist_kernel<<<N_BATCH * S_SAMP, 256, 0, stream>>>(inputs, samples, ws);
    min_sum_kernel<<<1, 64, 0, stream>>>(ws, out);
}

// Round 2
// 277.861 us; speedup vs baseline: 1.0209x; 1.0209x over previous
//
#include <hip/hip_runtime.h>

// inputs  [N=64, C=3, H=128, W=128] fp32  (12.6 MB, reused 16x -> cache-friendly)
// samples [N=64, S=16, C=3, H=128, W=128] fp32 (201 MB, streamed once -> nontemporal)
// out: scalar fp32 = sum_n min_s sum_chw (samples[n,s]-inputs[n])^2
constexpr int N_BATCH = 64;
constexpr int S_SAMP  = 16;
constexpr int CHW     = 3 * 128 * 128;   // 49152 floats per (n,s) pair
constexpr int CHW4    = CHW / 4;         // 12288 float4 (= 48 * 256)

typedef float v4f __attribute__((ext_vector_type(4)));

__device__ __forceinline__ float sqdiff4(v4f s, v4f p) {
    v4f d = s - p;
    return d.x * d.x + d.y * d.y + d.z * d.z + d.w * d.w;
}

// Kernel 1: one block per (n,s) pair. 1024 blocks x 256 threads (4 blocks/CU).
// 12 iterations x 4 independent (sample,input) float4 pairs = 8 loads in
// flight per thread, 4 accumulators. samples via nontemporal loads.
__global__ __launch_bounds__(256) void pair_sqdist_kernel(
    const float* __restrict__ inputs,
    const float* __restrict__ samples,
    float* __restrict__ ws)
{
    const int b = blockIdx.x;            // b = n*16 + s
    const int n = b >> 4;
    const v4f* __restrict__ inp = reinterpret_cast<const v4f*>(inputs + (size_t)n * CHW);
    const v4f* __restrict__ smp = reinterpret_cast<const v4f*>(samples + (size_t)b * CHW);

    const int t = threadIdx.x;
    float a0 = 0.f, a1 = 0.f, a2 = 0.f, a3 = 0.f;

    int i = t;
    #pragma unroll 1
    for (int k = 0; k < 12; ++k) {
        v4f s0 = __builtin_nontemporal_load(smp + i);
        v4f s1 = __builtin_nontemporal_load(smp + i + 256);
        v4f s2 = __builtin_nontemporal_load(smp + i + 512);
        v4f s3 = __builtin_nontemporal_load(smp + i + 768);
        v4f p0 = inp[i];
        v4f p1 = inp[i + 256];
        v4f p2 = inp[i + 512];
        v4f p3 = inp[i + 768];
        a0 += sqdiff4(s0, p0);
        a1 += sqdiff4(s1, p1);
        a2 += sqdiff4(s2, p2);
        a3 += sqdiff4(s3, p3);
        i += 1024;
    }
    float acc = (a0 + a1) + (a2 + a3);

    // wave-64 butterfly reduce
    #pragma unroll
    for (int off = 32; off > 0; off >>= 1)
        acc += __shfl_down(acc, off, 64);

    __shared__ float wave_part[4];
    const int wave = t >> 6;
    if ((t & 63) == 0) wave_part[wave] = acc;
    __syncthreads();
    if (t == 0) {
        ws[b] = wave_part[0] + wave_part[1] + wave_part[2] + wave_part[3];
    }
}

// Kernel 2: one block of 64 threads. Thread n: min over its 16 sample losses,
// then wave-64 sum reduce, lane 0 writes the scalar.
__global__ __launch_bounds__(64) void min_sum_kernel(
    const float* __restrict__ ws,
    float* __restrict__ out)
{
    const int n = threadIdx.x;           // 0..63
    const float* p = ws + n * S_SAMP;
    float m = p[0];
    #pragma unroll
    for (int s = 1; s < S_SAMP; ++s)
        m = fminf(m, p[s]);
    #pragma unroll
    for (int off = 32; off > 0; off >>= 1)
        m += __shfl_down(m, off, 64);
    if (n == 0) out[0] = m;
}

extern "C" void kernel_launch(void* const* d_in, const int* in_sizes, int n_in,
                              void* d_out, int out_size, void* d_ws, size_t ws_size,
                              hipStream_t stream) {
    const float* inputs  = (const float*)d_in[0];  // [64,3,128,128]
    const float* samples = (const float*)d_in[1];  // [64,16,3,128,128]
    float* out = (float*)d_out;                    // [1]
    float* ws  = (float*)d_ws;                     // uses 1024 floats = 4 KB

    pair_sqdist_kernel<<<N_BATCH * S_SAMP, 256, 0, stream>>>(inputs, samples, ws);
    min_sum_kernel<<<1, 64, 0, stream>>>(ws, out);
}